// Round 1
// baseline (143.837 us; speedup 1.0000x reference)
//
#include <hip/hip_runtime.h>
#include <math.h>

#define NL 8
#define NH 2048
#define NO 1000

__device__ __forceinline__ float dot4(float4 a, float4 b) {
    return a.x * b.x + a.y * b.y + a.z * b.z + a.w * b.w;
}

__device__ __forceinline__ float4 relu4(float4 a) {
    return make_float4(fmaxf(a.x, 0.f), fmaxf(a.y, 0.f), fmaxf(a.z, 0.f), fmaxf(a.w, 0.f));
}

__device__ __forceinline__ float wave_sum(float v) {
#pragma unroll
    for (int off = 32; off > 0; off >>= 1) v += __shfl_xor(v, off);
    return v;
}

// Kernel A: fused 6-GEMV + gate combine. One wave per (layer, row).
// grid = NL*NH/4 blocks of 256 threads (4 waves/block).
__global__ __launch_bounds__(256) void gru_gates_kernel(
    const float* __restrict__ x,    // [NH]
    const float* __restrict__ h,    // [NL, NH]
    const float* __restrict__ W_ir, const float* __restrict__ b_ir,
    const float* __restrict__ W_hr, const float* __restrict__ b_hr,
    const float* __restrict__ W_h1, const float* __restrict__ b_h1,
    const float* __restrict__ W_x1, const float* __restrict__ b_x1,
    const float* __restrict__ W_iu, const float* __restrict__ b_iu,
    const float* __restrict__ W_hu, const float* __restrict__ b_hu,
    float* __restrict__ new_h)      // [NL, NH]  (== d_out + NO)
{
    const int wave = (blockIdx.x * blockDim.x + threadIdx.x) >> 6;
    const int lane = threadIdx.x & 63;
    const int l   = wave >> 11;     // / NH
    const int row = wave & (NH - 1);

    // inp[0] = x, inp[l>0] = h[l-1]   (B == 1)
    const float4* vi = (const float4*)((l == 0) ? x : (h + (size_t)(l - 1) * NH));
    const float4* vh = (const float4*)(h + (size_t)l * NH);

    const size_t wbase = ((size_t)l * NH + row) * NH;
    const float4* wir = (const float4*)(W_ir + wbase);
    const float4* whr = (const float4*)(W_hr + wbase);
    const float4* wh1 = (const float4*)(W_h1 + wbase);
    const float4* wx1 = (const float4*)(W_x1 + wbase);
    const float4* wiu = (const float4*)(W_iu + wbase);
    const float4* whu = (const float4*)(W_hu + wbase);

    float s_ir = 0.f, s_hr = 0.f, s_h1 = 0.f, s_x1 = 0.f, s_iu = 0.f, s_hu = 0.f;
#pragma unroll
    for (int it = 0; it < NH / 4 / 64; ++it) {   // 8 iterations
        const int k = it * 64 + lane;            // float4 index
        const float4 a = vi[k];
        const float4 b = vh[k];
        s_ir += dot4(a, wir[k]);
        s_hr += dot4(b, whr[k]);
        s_h1 += dot4(b, wh1[k]);
        s_x1 += dot4(a, wx1[k]);
        s_iu += dot4(a, wiu[k]);
        s_hu += dot4(b, whu[k]);
    }
    s_ir = wave_sum(s_ir);
    s_hr = wave_sum(s_hr);
    s_h1 = wave_sum(s_h1);
    s_x1 = wave_sum(s_x1);
    s_iu = wave_sum(s_iu);
    s_hu = wave_sum(s_hu);

    if (lane == 0) {
        const int bi = l * NH + row;
        const float dir = s_ir + b_ir[bi];
        const float dhr = s_hr + b_hr[bi];
        const float dh1 = s_h1 + b_h1[bi];
        const float dx1 = s_x1 + b_x1[bi];
        const float diu = s_iu + b_iu[bi];
        const float dhu = s_hu + b_hu[bi];
        const float reset = 1.f / (1.f + expf(-(dir + dhr)));
        const float r     = tanhf(reset * dh1 + dx1);
        const float u     = 1.f / (1.f + expf(-(diu + dhu)));
        const float hv    = h[bi];
        new_h[bi] = (1.f - u) * r + u * hv;
    }
}

// Kernel B: FC GEMV on relu(new_h[last]). One wave per output row.
__global__ __launch_bounds__(256) void fc_kernel(
    const float* __restrict__ new_h,  // [NL, NH]
    const float* __restrict__ W_fc,   // [NO, NH]
    const float* __restrict__ b_fc,   // [NO]
    float* __restrict__ logits)       // [NO] (workspace)
{
    const int wave = (blockIdx.x * blockDim.x + threadIdx.x) >> 6;
    const int lane = threadIdx.x & 63;
    if (wave >= NO) return;
    const float4* v = (const float4*)(new_h + (size_t)(NL - 1) * NH);
    const float4* w = (const float4*)(W_fc + (size_t)wave * NH);
    float s = 0.f;
#pragma unroll
    for (int it = 0; it < NH / 4 / 64; ++it) {
        const int k = it * 64 + lane;
        s += dot4(relu4(v[k]), w[k]);
    }
    s = wave_sum(s);
    if (lane == 0) logits[wave] = s + b_fc[wave];
}

// Kernel C: log_softmax over NO=1000 elements, single block of 1024.
__global__ __launch_bounds__(1024) void lsm_kernel(
    const float* __restrict__ logits, float* __restrict__ out)
{
    const int t = threadIdx.x;
    const int lane = t & 63;
    const int wid = t >> 6;
    __shared__ float sred[16];

    const float v = (t < NO) ? logits[t] : -INFINITY;

    // block max
    float m = v;
#pragma unroll
    for (int off = 32; off > 0; off >>= 1) m = fmaxf(m, __shfl_xor(m, off));
    if (lane == 0) sred[wid] = m;
    __syncthreads();
    if (wid == 0) {
        float mm = (t < 16) ? sred[t] : -INFINITY;
#pragma unroll
        for (int off = 8; off > 0; off >>= 1) mm = fmaxf(mm, __shfl_xor(mm, off));
        if (t == 0) sred[0] = mm;
    }
    __syncthreads();
    const float M = sred[0];
    __syncthreads();

    // block sum of exp
    float e = (t < NO) ? expf(v - M) : 0.f;
    float s = e;
#pragma unroll
    for (int off = 32; off > 0; off >>= 1) s += __shfl_xor(s, off);
    if (lane == 0) sred[wid] = s;
    __syncthreads();
    if (wid == 0) {
        float ss = (t < 16) ? sred[t] : 0.f;
#pragma unroll
        for (int off = 8; off > 0; off >>= 1) ss += __shfl_xor(ss, off);
        if (t == 0) sred[0] = ss;
    }
    __syncthreads();
    const float lse = M + logf(sred[0]);

    if (t < NO) out[t] = v - lse;
}

extern "C" void kernel_launch(void* const* d_in, const int* in_sizes, int n_in,
                              void* d_out, int out_size, void* d_ws, size_t ws_size,
                              hipStream_t stream) {
    const float* x    = (const float*)d_in[0];
    const float* h    = (const float*)d_in[1];
    const float* W_ir = (const float*)d_in[2];
    const float* b_ir = (const float*)d_in[3];
    const float* W_hr = (const float*)d_in[4];
    const float* b_hr = (const float*)d_in[5];
    const float* W_h1 = (const float*)d_in[6];
    const float* b_h1 = (const float*)d_in[7];
    const float* W_x1 = (const float*)d_in[8];
    const float* b_x1 = (const float*)d_in[9];
    const float* W_iu = (const float*)d_in[10];
    const float* b_iu = (const float*)d_in[11];
    const float* W_hu = (const float*)d_in[12];
    const float* b_hu = (const float*)d_in[13];
    const float* W_fc = (const float*)d_in[14];
    const float* b_fc = (const float*)d_in[15];

    float* out    = (float*)d_out;      // [NO] log-softmax output
    float* new_h  = out + NO;           // [NL*NH] second tuple element
    float* logits = (float*)d_ws;       // [NO] scratch

    // Kernel A: NL*NH waves, 4 waves per 256-thread block.
    gru_gates_kernel<<<(NL * NH) / 4, 256, 0, stream>>>(
        x, h, W_ir, b_ir, W_hr, b_hr, W_h1, b_h1, W_x1, b_x1,
        W_iu, b_iu, W_hu, b_hu, new_h);

    // Kernel B: NO waves, 4 waves per block -> 250 blocks.
    fc_kernel<<<(NO + 3) / 4, 256, 0, stream>>>(new_h, W_fc, b_fc, logits);

    // Kernel C: single block log-softmax.
    lsm_kernel<<<1, 1024, 0, stream>>>(logits, out);
}